// Round 4
// baseline (355.160 us; speedup 1.0000x reference)
//
#include <hip/hip_runtime.h>
#include <cstdint>

#define CO   64
#define CI   32
#define HH   56
#define WW   56
#define LL   3136        // 56*56
#define KK   288         // 32*9
#define KH   144         // KK/2 — double-pumped LDS tile
#define NOUT 200704u     // 64*3136
#define TO   32          // outi-tile per block in fused fi1+cumsum

// flip threshold: u < 0.008f  <=>  ub < 67109*512
#define FLIP_LT 34359808u

// flip-list capacities. fi1: Binomial(4608,0.008) mean 37 sigma 6 -> 320 is ~47 sigma.
// fi2: Binomial(9216,0.008) mean 74 sigma 8.6 -> 320 is ~29 sigma. Unreachable.
#define FCAP1 320
#define FCAP2 320

// workspace layout: [0..63] atomic-max slots | 81920.. c_ws
// c_ws: float4 batches — c[k][outi] stored at [(k/4)*NOUT + outi]*4 + k%4
#define CWS_OFF_FLOATS 20480u                 // 81920 / 4
#define WS_NEED (81920ull + 4ull * 288ull * 200704ull)

__host__ __device__ inline uint32_t rotl32(uint32_t v, uint32_t r) {
#ifdef __HIP_DEVICE_COMPILE__
  return __builtin_amdgcn_alignbit(v, v, 32u - r);   // (v:v)>>(32-r) = rotl(v,r)
#else
  return (v << r) | (v >> (32u - r));
#endif
}

// ---------- threefry2x32 cipher, exact JAX rotation/key schedule ----------
__host__ __device__ inline void tf2x32(uint32_t k0, uint32_t k1,
                                       uint32_t x0, uint32_t x1,
                                       uint32_t& o0, uint32_t& o1) {
  uint32_t ks2 = k0 ^ k1 ^ 0x1BD11BDAu;
  uint32_t v0 = x0 + k0, v1 = x1 + k1;
#define TF_R(r) { v0 += v1; v1 = rotl32(v1, r); v1 ^= v0; }
  TF_R(13) TF_R(15) TF_R(26) TF_R(6)
  v0 += k1;  v1 += ks2 + 1u;
  TF_R(17) TF_R(29) TF_R(16) TF_R(24)
  v0 += ks2; v1 += k0 + 2u;
  TF_R(13) TF_R(15) TF_R(26) TF_R(6)
  v0 += k0;  v1 += k1 + 3u;
  TF_R(17) TF_R(29) TF_R(16) TF_R(24)
  v0 += k1;  v1 += ks2 + 4u;
  TF_R(13) TF_R(15) TF_R(26) TF_R(6)
  v0 += ks2; v1 += k0 + 5u;
#undef TF_R
  o0 = v0; o1 = v1;
}

// partitionable-threefry random bits for flat index i (hi word of iota = 0)
__device__ inline uint32_t rbits(uint32_t k0, uint32_t k1, uint32_t i) {
  uint32_t o0, o1;
  tf2x32(k0, k1, 0u, i, o0, o1);
  return o0 ^ o1;
}

// Markstein exact-division quantize step: rs must be RN(1/scale).
// Reproduces RN(x/scale); clamps dead because scale = max|x|/127+1e-12.
__device__ inline float qround(float xv, float scale, float rs) {
#pragma clang fp contract(off)
  float q0 = xv * rs;
  float er = fmaf(-scale, q0, xv);
  return rintf(fmaf(er, rs, q0));
}

// weight quantization, bit-identical to the original k_wquant body
__device__ inline float wquant(float wv, float scale_w) {
#pragma clang fp contract(off)
  float q = fminf(127.0f, fmaxf(-128.0f, rintf(wv / scale_w)));
  float y = q * scale_w;
  return wv + (y - wv);
}

// FI forward with wave-level pos-cipher skip (fallback path + passE).
__device__ inline float fi_fwd_skip(float x, float scale,
                                    uint32_t ub, uint32_t kp0, uint32_t kp1,
                                    uint32_t i0) {
#pragma clang fp contract(off)
  float q = rintf(x / scale);                    // round-half-even, IEEE div
  q = fminf(127.0f, fmaxf(-128.0f, q));
  bool flip = ub < FLIP_LT;
  float y;
  if (__any(flip)) {                             // wave-uniform branch
    uint32_t pb = rbits(kp0, kp1, i0);
    uint32_t qt = ((uint32_t)(int)q) & 0xFFu;
    uint32_t mask = flip ? (1u << (pb & 7u)) : 0u;
    uint32_t qf = qt ^ mask;
    float qs = (float)(int)(signed char)(qf);
    y = qs * scale;
  } else {
    y = q * scale;
  }
  return x + (y - x);                            // x + stop_grad(y - x)
}

template <int BS>
__device__ inline float block_max(float v) {
  __shared__ float s[BS];
  int t = threadIdx.x;
  __syncthreads();
  s[t] = v; __syncthreads();
  for (int o = BS / 2; o > 0; o >>= 1) {
    if (t < o) s[t] = fmaxf(s[t], s[t + o]);
    __syncthreads();
  }
  return s[0];
}

// ---------- kernel 1: max|p| (+ publishes max|w| for later kernels) ----------
// Every block computes the identical full max|w| reduction (18432 elems, same
// order -> same bits), so scale_w is available in-kernel with no prior launch.
__global__ __launch_bounds__(256) void k_maxp(const float* __restrict__ x,
                                              const float* __restrict__ w,
                                              unsigned int* __restrict__ scal) {
#pragma clang fp contract(off)
  float mwall = 0.f;
  for (int i = threadIdx.x; i < CO * KK; i += 256) mwall = fmaxf(mwall, fabsf(w[i]));
  mwall = block_max<256>(mwall);
  float scale_w = mwall / 127.0f + 1e-12f;
  if (threadIdx.x == 0 && blockIdx.x == 0) scal[0] = __float_as_uint(mwall);

  int k = blockIdx.x;                       // 0..287
  int ci = k / 9, r = k % 9, di = r / 3, dj = r % 3;
  const float* xr = x + ci * LL;
  float mx = 0.f;
  for (int l = threadIdx.x; l < LL; l += 256) {
    int oy = l / WW, ox = l % WW;
    int yy = oy + di - 1, xx = ox + dj - 1;
    float v = (yy >= 0 && yy < HH && xx >= 0 && xx < WW) ? xr[yy * WW + xx] : 0.f;
    mx = fmaxf(mx, fabsf(v));
  }
  float mw = 0.f;
  for (int co = threadIdx.x; co < CO; co += 256)
    mw = fmaxf(mw, fabsf(wquant(w[co * KK + k], scale_w)));
  mx = block_max<256>(mx);
  mw = block_max<256>(mw);
  if (threadIdx.x == 0) atomicMax(scal + 1, __float_as_uint(mx * mw));
}

// ---------- k_fi1cs: fused FI1 + serial cumsum, double-pumped LDS tile ----------
// Skip-path everywhere + LDS flip-list; dense fix pass before the fold keeps c
// bit-exact.
__global__ __launch_bounds__(256) void k_fi1cs(const float* __restrict__ x,
                                               const float* __restrict__ w,
                                               const unsigned int* __restrict__ scal,
                                               unsigned int* __restrict__ maxc_bits,
                                               float* __restrict__ cws,
                                               uint32_t ku0, uint32_t ku1,
                                               uint32_t kp0, uint32_t kp1) {
#pragma clang fp contract(off)
  __shared__ float sW[KK];                  // 1152 B
  __shared__ float sP[KH][TO];              // 18432 B
  __shared__ uint32_t sCnt;
  __shared__ uint32_t sMeta[FCAP1];         // (k<<5)|o
  __shared__ float    sVal[FCAP1];          // p value of flipped element
  int tid = threadIdx.x;
  uint32_t outi0 = blockIdx.x * (uint32_t)TO;
  int co = (int)(outi0 / (uint32_t)LL);     // block-uniform (32 | 3136)
  float scale_w = __uint_as_float(scal[0]) / 127.0f + 1e-12f;
  for (int i = tid; i < KK; i += 256) sW[i] = wquant(w[co * KK + i], scale_w);
  if (tid == 0) sCnt = 0u;
  __syncthreads();

  int o = tid & 31, s = tid >> 5;           // s in 0..7
  uint32_t outi = outi0 + (uint32_t)o;
  int l = (int)(outi - (uint32_t)co * LL);
  int oy = l / WW, ox = l % WW;
  float scale_p = __uint_as_float(scal[1]) / 127.0f + 1e-12f;
  float rs_p = 1.0f / scale_p;              // RN reciprocal, once per thread
  uint32_t ibase = outi * (uint32_t)KK;

  float carry = 0.f, maxc = 0.f;
  for (int half = 0; half < 2; ++half) {
    int kbase = half * KH;
    int k = kbase + s * 18;
    int ci0 = k / 9;                        // = 16*half + 2*s
    for (int c2 = 0; c2 < 2; ++c2) {
      const float* xr = x + (ci0 + c2) * LL;
      float xv[9];
      uint32_t ub[9];
#pragma unroll
      for (int di = 0; di < 3; ++di) {
        int yy = oy + di - 1;
        bool yok = (yy >= 0) && (yy < HH);
#pragma unroll
        for (int dj = 0; dj < 3; ++dj) {
          int xx = ox + dj - 1;
          xv[di * 3 + dj] = (yok && xx >= 0 && xx < WW) ? xr[yy * WW + xx] : 0.f;
        }
      }
#pragma unroll
      for (int j = 0; j < 9; ++j)           // 9 independent cipher chains
        ub[j] = rbits(ku0, ku1, ibase + (uint32_t)(k + j));
#pragma unroll
      for (int j = 0; j < 9; ++j) {
        float p = xv[j] * sW[k + j];
        float q = qround(p, scale_p, rs_p); // exact RN(p/scale_p), clamp dead
        float y = q * scale_p;
        sP[k + j - kbase][o] = p + (y - p); // skip-path fi value
        bool flip = ub[j] < FLIP_LT;
        if (__any(flip)) {                  // vcc branch, no exec write when clear
          if (flip) {
            uint32_t idx = atomicAdd(&sCnt, 1u);
            if (idx < FCAP1) {
              sMeta[idx] = ((uint32_t)(k + j) << 5) | (uint32_t)o;
              sVal[idx] = p;
            }
          }
        }
      }
      k += 9;
    }
    __syncthreads();
    // fix pass: dense pos-cipher for the ~37 flipped elements of this half
    {
      uint32_t n = sCnt; if (n > FCAP1) n = FCAP1;
      for (uint32_t i2 = (uint32_t)tid; i2 < n; i2 += 256u) {
        uint32_t meta = sMeta[i2];
        float p = sVal[i2];
        uint32_t kg = meta >> 5, oo = meta & 31u;
        uint32_t i0 = (outi0 + oo) * (uint32_t)KK + kg;
        uint32_t pb = rbits(kp0, kp1, i0);
        float q = qround(p, scale_p, rs_p);
        uint32_t qt = ((uint32_t)(int)q) & 0xFFu;
        uint32_t qf = qt ^ (1u << (pb & 7u));
        float qs = (float)(int)(signed char)(qf);
        float yv = qs * scale_p;
        sP[kg - (uint32_t)kbase][oo] = p + (yv - p);   // exact flip value
      }
    }
    __syncthreads();
    // Phase 2: lanes 0..31 fold this half's 144 rows, carry held in register.
    if (tid < TO) {
      float c = carry;
#pragma unroll 8
      for (int kk = 0; kk < KH; ++kk) {
        c += sP[kk][tid];                   // exact reference fold order
        sP[kk][tid] = c;
        maxc = fmaxf(maxc, fabsf(c));
      }
      carry = c;
    }
    if (tid == 255) sCnt = 0u;              // reset for next half (disjoint from fold)
    __syncthreads();
    // Phase 3: write-out, float4-batch layout.
    // c[k][outi] -> cws[((k/4)*NOUT + outi)*4 + k%4]
    for (int b = s; b < 36; b += 8) {
      int gb = half * 36 + b;
      float4 v0 = {sP[b * 4 + 0][o], sP[b * 4 + 1][o],
                   sP[b * 4 + 2][o], sP[b * 4 + 3][o]};
      float* op = cws + ((size_t)gb * NOUT + outi) * 4u;
      *(float4*)op = v0;
    }
    __syncthreads();                        // next half overwrites sP
  }
  // maxc lives in lanes 0..31 of wave 0; lanes 32..63 hold 0 -> full-wave reduce.
  if (tid < 64) {
#pragma unroll
    for (int off = 32; off > 0; off >>= 1)
      maxc = fmaxf(maxc, __shfl_down(maxc, off));
    if (tid == 0) atomicMax(maxc_bits, __float_as_uint(maxc));
  }
}

// ---------- k_fi2split: FI2 on c — 32 outi x 8 k-groups, grid 6272 ----------
// Rolled loop, float4 batches. k=0 exclusion and k=287->ys are post-loop
// corrections (recompute + subtract, cancellation to reassociation-ulp).
// Flip fix pass drops kx==0 and routes kx==287 to the ys-correction slot.
__global__ __launch_bounds__(256) void k_fi2split(const float* __restrict__ cws,
                                                  const unsigned int* __restrict__ scal,
                                                  unsigned int* __restrict__ maxy_bits,
                                                  float* __restrict__ yout,
                                                  uint32_t ku0, uint32_t ku1,
                                                  uint32_t kp0, uint32_t kp1) {
#pragma clang fp contract(off)
  __shared__ float sE[8][TO];
  __shared__ float sYs[TO];
  __shared__ float sEC[TO];                 // flip corrections to e
  __shared__ float sYsC[TO];                // flip correction to ys (k=287)
  __shared__ uint32_t sCnt;
  __shared__ uint32_t sMeta[FCAP2];         // (k<<5)|o
  __shared__ float    sVal[FCAP2];          // c value of flipped element
  int tid = threadIdx.x;
  int o = tid & 31;
  int kg = tid >> 5;                        // 0..7
  if (tid < TO) { sEC[tid] = 0.f; sYsC[tid] = 0.f; }
  if (tid == 0) sCnt = 0u;
  __syncthreads();
  uint32_t outi = blockIdx.x * (uint32_t)TO + (uint32_t)o;   // 6272*32 = NOUT
  float scale_c = __uint_as_float(scal[2]) / 127.0f + 1e-12f;
  float rs_c = 1.0f / scale_c;
  uint32_t ibb = outi * (uint32_t)KK;
  const size_t BSTR = (size_t)NOUT * 4u;    // float stride between k-batches
  float e = 0.f;

  int b0 = kg * 9;                          // 9 float4-batches (36 k's) per group
  const float* bp = cws + (size_t)outi * 4u + (size_t)b0 * BSTR;
  uint32_t ib = ibb + (uint32_t)(b0 * 4);
  uint32_t kbm = (uint32_t)(b0 * 4);
  for (int b = 0; b < 9; ++b) {
    float4 A = *(const float4*)bp;
    float c4[4] = {A.x, A.y, A.z, A.w};
    uint32_t ub[4];
#pragma unroll
    for (int j = 0; j < 4; ++j) ub[j] = rbits(ku0, ku1, ib + (uint32_t)j);
#pragma unroll
    for (int j = 0; j < 4; ++j) {
      float c = c4[j];
      float q = qround(c, scale_c, rs_c);   // exact RN(c/scale_c), clamp dead
      float y = q * scale_c;
      float cf = c + (y - c);               // skip-path fi value
      e += (cf - c);
      bool flip = ub[j] < FLIP_LT;
      if (__any(flip)) {                    // vcc branch, no exec write when clear
        if (flip) {
          uint32_t idx = atomicAdd(&sCnt, 1u);
          if (idx < FCAP2) {
            sMeta[idx] = ((kbm + (uint32_t)j) << 5) | (uint32_t)o;
            sVal[idx] = c;
          }
        }
      }
    }
    bp += BSTR; ib += 4u; kbm += 4u;
  }

  float ys = 0.f;
  if (kg == 0) {
    // remove the k=0 skip term the loop added (reference excludes k=0 entirely)
    float c0 = cws[(size_t)outi * 4u];
    float q = qround(c0, scale_c, rs_c);
    float y = q * scale_c;
    float cf = c0 + (y - c0);
    e -= (cf - c0);
  } else if (kg == 7) {
    // reclaim k=287: loop added its skip term to e; it belongs to ys instead
    float c287 = cws[(size_t)outi * 4u + 71u * BSTR + 3u];
    float q = qround(c287, scale_c, rs_c);
    float y = q * scale_c;
    float cf = c287 + (y - c287);
    e -= (cf - c287);
    ys = cf;
  }
  sE[kg][o] = e;
  if (kg == 7) sYs[o] = ys;
  __syncthreads();
  // fix pass: dense pos-cipher for the ~74 flipped elements of this block
  {
    uint32_t n = sCnt; if (n > FCAP2) n = FCAP2;
    for (uint32_t i2 = (uint32_t)tid; i2 < n; i2 += 256u) {
      uint32_t meta = sMeta[i2];
      float c = sVal[i2];
      uint32_t kx = meta >> 5, ln = meta & 31u;
      uint32_t i0 = (blockIdx.x * (uint32_t)TO + ln) * (uint32_t)KK + kx;
      uint32_t pb = rbits(kp0, kp1, i0);
      float q = qround(c, scale_c, rs_c);
      uint32_t qt = ((uint32_t)(int)q) & 0xFFu;
      uint32_t qf = qt ^ (1u << (pb & 7u));
      float qs = (float)(int)(signed char)(qf);
      float yf = qs * scale_c;
      float cff = c + (yf - c);             // flip-path fi value
      float ysk = q * scale_c;
      float cfs = c + (ysk - c);            // skip value already folded into e/ys
      float corr = cff - cfs;
      if (kx == 287u)     sYsC[ln] = corr;  // unique writer per lane
      else if (kx != 0u)  atomicAdd(&sEC[ln], corr);
      // kx == 0: reference drops c_fi[0] entirely -> no correction
    }
  }
  __syncthreads();
  float maxy = 0.f;
  if (tid < TO) {
    float ee = sE[0][o];
#pragma unroll
    for (int g = 1; g < 8; ++g) ee += sE[g][o];
    float y = (sYs[o] + sYsC[o]) + (ee + sEC[o]);
    yout[outi] = y;
    maxy = fabsf(y);
  }
  maxy = block_max<256>(maxy);
  if (tid == 0) atomicMax(maxy_bits, __float_as_uint(maxy));
}

// ---------- fallback (small ws): fused FI1+cumsum, then recompute-FI2 ----------
__global__ __launch_bounds__(64) void k_passC_nostore(const float* __restrict__ x,
                                                      const float* __restrict__ w,
                                                      const unsigned int* __restrict__ scal,
                                                      unsigned int* __restrict__ maxc_bits,
                                                      uint32_t ku0, uint32_t ku1,
                                                      uint32_t kp0, uint32_t kp1) {
#pragma clang fp contract(off)
  __shared__ float sW[KK];
  int co = blockIdx.y;
  float scale_w = __uint_as_float(scal[0]) / 127.0f + 1e-12f;
  for (int i = threadIdx.x; i < KK; i += 64) sW[i] = wquant(w[co * KK + i], scale_w);
  __syncthreads();
  int l = blockIdx.x * 64 + threadIdx.x;
  float maxc = 0.f;
  if (l < LL) {
    float scale_p = __uint_as_float(scal[1]) / 127.0f + 1e-12f;
    int oy = l / WW, ox = l % WW;
    uint32_t base = (uint32_t)(co * LL + l) * KK;
    float c = 0.f;
    int k = 0;
    for (int ci = 0; ci < CI; ++ci) {
      const float* xr = x + ci * LL;
#pragma unroll
      for (int di = 0; di < 3; ++di) {
        int yy = oy + di - 1;
        bool yok = (yy >= 0) && (yy < HH);
#pragma unroll
        for (int dj = 0; dj < 3; ++dj, ++k) {
          int xx = ox + dj - 1;
          float xv = (yok && xx >= 0 && xx < WW) ? xr[yy * WW + xx] : 0.f;
          float p = xv * sW[k];
          uint32_t i0 = base + (uint32_t)k;
          uint32_t ub = rbits(ku0, ku1, i0);
          c += fi_fwd_skip(p, scale_p, ub, kp0, kp1, i0);
          maxc = fmaxf(maxc, fabsf(c));
        }
      }
    }
  }
  maxc = block_max<64>(maxc);
  if (threadIdx.x == 0) atomicMax(maxc_bits, __float_as_uint(maxc));
}

__global__ __launch_bounds__(256) void k_passD_rec(const float* __restrict__ x,
                                                   const float* __restrict__ w,
                                                   const unsigned int* __restrict__ scal,
                                                   unsigned int* __restrict__ maxy_bits,
                                                   float* __restrict__ yout,
                                                   uint32_t ku10, uint32_t ku11,
                                                   uint32_t kp10, uint32_t kp11,
                                                   uint32_t ku20, uint32_t ku21,
                                                   uint32_t kp20, uint32_t kp21) {
#pragma clang fp contract(off)
  __shared__ float sW[KK];
  int co = blockIdx.y;
  float scale_w = __uint_as_float(scal[0]) / 127.0f + 1e-12f;
  for (int i = threadIdx.x; i < KK; i += 256) sW[i] = wquant(w[co * KK + i], scale_w);
  __syncthreads();
  int l = blockIdx.x * 256 + threadIdx.x;
  float maxy = 0.f;
  if (l < LL) {
    float scale_p = __uint_as_float(scal[1]) / 127.0f + 1e-12f;
    float scale_c = __uint_as_float(scal[2]) / 127.0f + 1e-12f;
    int oy = l / WW, ox = l % WW;
    uint32_t base = (uint32_t)(co * LL + l) * KK;
    float c = 0.f, e = 0.f, ys = 0.f;
    int k = 0;
    for (int ci = 0; ci < CI; ++ci) {
      const float* xr = x + ci * LL;
#pragma unroll
      for (int di = 0; di < 3; ++di) {
        int yy = oy + di - 1;
        bool yok = (yy >= 0) && (yy < HH);
#pragma unroll
        for (int dj = 0; dj < 3; ++dj, ++k) {
          int xx = ox + dj - 1;
          float xv = (yok && xx >= 0 && xx < WW) ? xr[yy * WW + xx] : 0.f;
          float p = xv * sW[k];
          uint32_t i0 = base + (uint32_t)k;
          uint32_t ub1 = rbits(ku10, ku11, i0);
          c += fi_fwd_skip(p, scale_p, ub1, kp10, kp11, i0);
          uint32_t ub2 = rbits(ku20, ku21, i0);
          float cf = fi_fwd_skip(c, scale_c, ub2, kp20, kp21, i0);
          if (k >= 1 && k <= 286) e += (cf - c);
          if (k == 287)           ys = cf;
        }
      }
    }
    float y = ys + e;
    yout[co * LL + l] = y;
    maxy = fabsf(y);
  }
  maxy = block_max<256>(maxy);
  if (threadIdx.x == 0) atomicMax(maxy_bits, __float_as_uint(maxy));
}

// ---------- pass E: FI3 on y, in place in d_out ----------
__global__ __launch_bounds__(256) void k_passE(float* __restrict__ y,
                                               const unsigned int* __restrict__ scal,
                                               uint32_t ku0, uint32_t ku1,
                                               uint32_t kp0, uint32_t kp1) {
#pragma clang fp contract(off)
  uint32_t i = blockIdx.x * 256u + threadIdx.x;
  float scale_y = __uint_as_float(scal[3]) / 127.0f + 1e-12f;
  uint32_t ub = rbits(ku0, ku1, i);
  y[i] = fi_fwd_skip(y[i], scale_y, ub, kp0, kp1, i);
}

extern "C" void kernel_launch(void* const* d_in, const int* in_sizes, int n_in,
                              void* d_out, int out_size, void* d_ws, size_t ws_size,
                              hipStream_t stream) {
  const float* x = (const float*)d_in[0];   // (1,32,56,56)
  const float* w = (const float*)d_in[1];   // (64,32,3,3)
  float* out = (float*)d_out;               // (1,64,56,56)

  unsigned int* scal = (unsigned int*)d_ws; // [0]=max|w| [1]=max|p| [2]=max|c| [3]=max|y|
  float* cws = (float*)d_ws + CWS_OFF_FLOATS;
  bool bigws = ws_size >= WS_NEED;          // constant across calls -> graph-safe

  // ---- exact JAX key derivation, partitionable threefry ----
  uint32_t K1[2], K2[2], K3[2];
  tf2x32(0u, 42u, 0u, 0u, K1[0], K1[1]);    // split(key(42), 3)
  tf2x32(0u, 42u, 0u, 1u, K2[0], K2[1]);
  tf2x32(0u, 42u, 0u, 2u, K3[0], K3[1]);
  auto derive = [](const uint32_t kk[2], uint32_t U[2], uint32_t P[2]) {
    uint32_t kA0, kA1, kB0, kB1, t0, t1;
    tf2x32(kk[0], kk[1], 0u, 0u, kA0, kA1); // split(key,2)[0] -> uniform key
    tf2x32(kk[0], kk[1], 0u, 1u, kB0, kB1); // split(key,2)[1] -> randint key
    U[0] = kA0; U[1] = kA1;
    tf2x32(kB0, kB1, 0u, 1u, t0, t1);       // randint lower-bits key
    P[0] = t0; P[1] = t1;
  };
  uint32_t U1[2],P1[2],U2[2],P2[2],U3[2],P3[2];
  derive(K1, U1, P1); derive(K2, U2, P2); derive(K3, U3, P3);

  hipMemsetAsync(d_ws, 0, 64, stream);      // zero the atomic-max slots

  k_maxp<<<KK, 256, 0, stream>>>(x, w, scal);
  if (bigws) {
    k_fi1cs<<<NOUT / TO, 256, 0, stream>>>(x, w, scal, scal + 2, cws,
                                           U1[0], U1[1], P1[0], P1[1]);
    k_fi2split<<<NOUT / TO, 256, 0, stream>>>(cws, scal, scal + 3, out,
                                              U2[0], U2[1], P2[0], P2[1]);
  } else {
    dim3 gC(49, 64);
    k_passC_nostore<<<gC, 64, 0, stream>>>(x, w, scal, scal + 2,
                                           U1[0], U1[1], P1[0], P1[1]);
    dim3 gR(13, 64);
    k_passD_rec<<<gR, 256, 0, stream>>>(x, w, scal, scal + 3, out,
                                        U1[0], U1[1], P1[0], P1[1],
                                        U2[0], U2[1], P2[0], P2[1]);
  }
  k_passE<<<NOUT / 256, 256, 0, stream>>>(out, scal,
                                          U3[0], U3[1], P3[0], P3[1]);
}

// Round 5
// 343.818 us; speedup vs baseline: 1.0330x; 1.0330x over previous
//
#include <hip/hip_runtime.h>
#include <cstdint>

#define CO   64
#define CI   32
#define HH   56
#define WW   56
#define LL   3136        // 56*56
#define KK   288         // 32*9
#define KH   144         // KK/2 — double-pumped LDS tile
#define NOUT 200704u     // 64*3136
#define TO   32          // outi-tile per block

// flip threshold: u < 0.008f  <=>  ub < 67109*512
#define FLIP_LT 34359808u

// flip-list capacities. fi1: Binomial(4608,0.008) mean 37 -> 320 is ~47 sigma.
// fi2: Binomial(9216,0.008) mean 74 -> 320 is ~29 sigma. Unreachable.
#define FCAP1 320
#define FCAP2 320

// workspace layout: [0..63] atomic-max slots | 81920.. c_ws
// c_ws: float4 batches — c[k][outi] stored at [(k/4)*NOUT + outi]*4 + k%4
#define CWS_OFF_FLOATS 20480u                 // 81920 / 4
#define WS_NEED (81920ull + 4ull * 288ull * 200704ull)

__host__ __device__ inline uint32_t rotl32(uint32_t v, uint32_t r) {
#ifdef __HIP_DEVICE_COMPILE__
  return __builtin_amdgcn_alignbit(v, v, 32u - r);   // (v:v)>>(32-r) = rotl(v,r)
#else
  return (v << r) | (v >> (32u - r));
#endif
}

// ---------- threefry2x32 cipher, exact JAX rotation/key schedule ----------
__host__ __device__ inline void tf2x32(uint32_t k0, uint32_t k1,
                                       uint32_t x0, uint32_t x1,
                                       uint32_t& o0, uint32_t& o1) {
  uint32_t ks2 = k0 ^ k1 ^ 0x1BD11BDAu;
  uint32_t v0 = x0 + k0, v1 = x1 + k1;
#define TF_R(r) { v0 += v1; v1 = rotl32(v1, r); v1 ^= v0; }
  TF_R(13) TF_R(15) TF_R(26) TF_R(6)
  v0 += k1;  v1 += ks2 + 1u;
  TF_R(17) TF_R(29) TF_R(16) TF_R(24)
  v0 += ks2; v1 += k0 + 2u;
  TF_R(13) TF_R(15) TF_R(26) TF_R(6)
  v0 += k0;  v1 += k1 + 3u;
  TF_R(17) TF_R(29) TF_R(16) TF_R(24)
  v0 += k1;  v1 += ks2 + 4u;
  TF_R(13) TF_R(15) TF_R(26) TF_R(6)
  v0 += ks2; v1 += k0 + 5u;
#undef TF_R
  o0 = v0; o1 = v1;
}

// partitionable-threefry random bits for flat index i (hi word of iota = 0)
__device__ inline uint32_t rbits(uint32_t k0, uint32_t k1, uint32_t i) {
  uint32_t o0, o1;
  tf2x32(k0, k1, 0u, i, o0, o1);
  return o0 ^ o1;
}

// N ciphers for consecutive indices ibase..ibase+N-1, computed in SoA
// lockstep: every round macro touches all N chains, forcing the register
// allocator to keep all chain states live and the scheduler to interleave
// them (hides the ~4-cycle dependent-op latency within one wave).
// Bit-identical per element to rbits(): same ops, chains are independent.
template <int N>
__device__ inline void rbits_n(uint32_t k0, uint32_t k1, uint32_t ibase,
                               uint32_t out[N]) {
  uint32_t ks2 = k0 ^ k1 ^ 0x1BD11BDAu;
  uint32_t v0[N], v1[N];
#pragma unroll
  for (int j = 0; j < N; ++j) { v0[j] = k0; v1[j] = (ibase + (uint32_t)j) + k1; }
#define TFN_R(r) { _Pragma("unroll") \
  for (int j = 0; j < N; ++j) { v0[j] += v1[j]; v1[j] = rotl32(v1[j], (r)); v1[j] ^= v0[j]; } }
#define TFN_K(a, b, c) { _Pragma("unroll") \
  for (int j = 0; j < N; ++j) { v0[j] += (a); v1[j] += (b) + (c); } }
  TFN_R(13) TFN_R(15) TFN_R(26) TFN_R(6)  TFN_K(k1, ks2, 1u)
  TFN_R(17) TFN_R(29) TFN_R(16) TFN_R(24) TFN_K(ks2, k0, 2u)
  TFN_R(13) TFN_R(15) TFN_R(26) TFN_R(6)  TFN_K(k0, k1, 3u)
  TFN_R(17) TFN_R(29) TFN_R(16) TFN_R(24) TFN_K(k1, ks2, 4u)
  TFN_R(13) TFN_R(15) TFN_R(26) TFN_R(6)  TFN_K(ks2, k0, 5u)
#undef TFN_R
#undef TFN_K
#pragma unroll
  for (int j = 0; j < N; ++j) out[j] = v0[j] ^ v1[j];
}

// Markstein exact-division quantize step: rs must be RN(1/scale).
// Reproduces RN(x/scale); clamps dead because scale = max|x|/127+1e-12.
__device__ inline float qround(float xv, float scale, float rs) {
#pragma clang fp contract(off)
  float q0 = xv * rs;
  float er = fmaf(-scale, q0, xv);
  return rintf(fmaf(er, rs, q0));
}

// weight quantization, bit-identical to the original k_wquant body
__device__ inline float wquant(float wv, float scale_w) {
#pragma clang fp contract(off)
  float q = fminf(127.0f, fmaxf(-128.0f, rintf(wv / scale_w)));
  float y = q * scale_w;
  return wv + (y - wv);
}

// FI forward with wave-level pos-cipher skip (fallback path + passE).
__device__ inline float fi_fwd_skip(float x, float scale,
                                    uint32_t ub, uint32_t kp0, uint32_t kp1,
                                    uint32_t i0) {
#pragma clang fp contract(off)
  float q = rintf(x / scale);                    // round-half-even, IEEE div
  q = fminf(127.0f, fmaxf(-128.0f, q));
  bool flip = ub < FLIP_LT;
  float y;
  if (__any(flip)) {                             // wave-uniform branch
    uint32_t pb = rbits(kp0, kp1, i0);
    uint32_t qt = ((uint32_t)(int)q) & 0xFFu;
    uint32_t mask = flip ? (1u << (pb & 7u)) : 0u;
    uint32_t qf = qt ^ mask;
    float qs = (float)(int)(signed char)(qf);
    y = qs * scale;
  } else {
    y = q * scale;
  }
  return x + (y - x);                            // x + stop_grad(y - x)
}

template <int BS>
__device__ inline float block_max(float v) {
  __shared__ float s[BS];
  int t = threadIdx.x;
  __syncthreads();
  s[t] = v; __syncthreads();
  for (int o = BS / 2; o > 0; o >>= 1) {
    if (t < o) s[t] = fmaxf(s[t], s[t + o]);
    __syncthreads();
  }
  return s[0];
}

// ---------- kernel 1: max|w| (tiny, 72 blocks) ----------
__global__ __launch_bounds__(256) void k_wmax(const float* __restrict__ w,
                                              unsigned int* __restrict__ mbits) {
  int i = blockIdx.x * 256 + threadIdx.x;        // grid 72 -> exactly 18432
  float m = fabsf(w[i]);
  m = block_max<256>(m);
  if (threadIdx.x == 0) atomicMax(mbits, __float_as_uint(m));
}

// ---------- kernel 2: max|p| = max_k (max_l|xc[l,k]| * max_co|wq[co,k]|) -------
__global__ __launch_bounds__(256) void k_maxp(const float* __restrict__ x,
                                              const float* __restrict__ w,
                                              const unsigned int* __restrict__ scal,
                                              unsigned int* __restrict__ maxp_bits) {
#pragma clang fp contract(off)
  int k = blockIdx.x;                       // 0..287
  int ci = k / 9, r = k % 9, di = r / 3, dj = r % 3;
  const float* xr = x + ci * LL;
  float scale_w = __uint_as_float(scal[0]) / 127.0f + 1e-12f;
  float mx = 0.f;
  for (int l = threadIdx.x; l < LL; l += 256) {
    int oy = l / WW, ox = l % WW;
    int yy = oy + di - 1, xx = ox + dj - 1;
    float v = (yy >= 0 && yy < HH && xx >= 0 && xx < WW) ? xr[yy * WW + xx] : 0.f;
    mx = fmaxf(mx, fabsf(v));
  }
  float mw = 0.f;
  for (int co = threadIdx.x; co < CO; co += 256)
    mw = fmaxf(mw, fabsf(wquant(w[co * KK + k], scale_w)));
  mx = block_max<256>(mx);
  mw = block_max<256>(mw);
  if (threadIdx.x == 0) atomicMax(maxp_bits, __float_as_uint(mx * mw));
}

// ---------- k_fi1cs: fused FI1 + serial cumsum, double-pumped LDS tile ----------
// Skip-path everywhere + LDS flip-list; dense fix pass before the fold keeps c
// bit-exact. Ciphers computed 9-wide SoA for in-wave ILP.
__global__ __launch_bounds__(256) void k_fi1cs(const float* __restrict__ x,
                                               const float* __restrict__ w,
                                               const unsigned int* __restrict__ scal,
                                               unsigned int* __restrict__ maxc_bits,
                                               float* __restrict__ cws,
                                               uint32_t ku0, uint32_t ku1,
                                               uint32_t kp0, uint32_t kp1) {
#pragma clang fp contract(off)
  __shared__ float sW[KK];                  // 1152 B
  __shared__ float sP[KH][TO];              // 18432 B
  __shared__ uint32_t sCnt;
  __shared__ uint32_t sMeta[FCAP1];         // (k<<5)|o
  __shared__ float    sVal[FCAP1];          // p value of flipped element
  int tid = threadIdx.x;
  uint32_t outi0 = blockIdx.x * (uint32_t)TO;
  int co = (int)(outi0 / (uint32_t)LL);     // block-uniform (32 | 3136)
  float scale_w = __uint_as_float(scal[0]) / 127.0f + 1e-12f;
  for (int i = tid; i < KK; i += 256) sW[i] = wquant(w[co * KK + i], scale_w);
  if (tid == 0) sCnt = 0u;
  __syncthreads();

  int o = tid & 31, s = tid >> 5;           // s in 0..7
  uint32_t outi = outi0 + (uint32_t)o;
  int l = (int)(outi - (uint32_t)co * LL);
  int oy = l / WW, ox = l % WW;
  float scale_p = __uint_as_float(scal[1]) / 127.0f + 1e-12f;
  float rs_p = 1.0f / scale_p;              // RN reciprocal, once per thread
  uint32_t ibase = outi * (uint32_t)KK;

  float carry = 0.f, maxc = 0.f;
  for (int half = 0; half < 2; ++half) {
    int kbase = half * KH;
    int k = kbase + s * 18;
    int ci0 = k / 9;                        // = 16*half + 2*s
    for (int c2 = 0; c2 < 2; ++c2) {
      const float* xr = x + (ci0 + c2) * LL;
      float xv[9];
      uint32_t ub[9];
#pragma unroll
      for (int di = 0; di < 3; ++di) {
        int yy = oy + di - 1;
        bool yok = (yy >= 0) && (yy < HH);
#pragma unroll
        for (int dj = 0; dj < 3; ++dj) {
          int xx = ox + dj - 1;
          xv[di * 3 + dj] = (yok && xx >= 0 && xx < WW) ? xr[yy * WW + xx] : 0.f;
        }
      }
      rbits_n<9>(ku0, ku1, ibase + (uint32_t)k, ub);   // 9 interleaved chains
#pragma unroll
      for (int j = 0; j < 9; ++j) {
        float p = xv[j] * sW[k + j];
        float q = qround(p, scale_p, rs_p); // exact RN(p/scale_p), clamp dead
        float y = q * scale_p;
        sP[k + j - kbase][o] = p + (y - p); // skip-path fi value
        bool flip = ub[j] < FLIP_LT;
        if (__any(flip)) {                  // vcc branch, no exec write when clear
          if (flip) {
            uint32_t idx = atomicAdd(&sCnt, 1u);
            if (idx < FCAP1) {
              sMeta[idx] = ((uint32_t)(k + j) << 5) | (uint32_t)o;
              sVal[idx] = p;
            }
          }
        }
      }
      k += 9;
    }
    __syncthreads();
    // fix pass: dense pos-cipher for the ~37 flipped elements of this half
    {
      uint32_t n = sCnt; if (n > FCAP1) n = FCAP1;
      for (uint32_t i2 = (uint32_t)tid; i2 < n; i2 += 256u) {
        uint32_t meta = sMeta[i2];
        float p = sVal[i2];
        uint32_t kg = meta >> 5, oo = meta & 31u;
        uint32_t i0 = (outi0 + oo) * (uint32_t)KK + kg;
        uint32_t pb = rbits(kp0, kp1, i0);
        float q = qround(p, scale_p, rs_p);
        uint32_t qt = ((uint32_t)(int)q) & 0xFFu;
        uint32_t qf = qt ^ (1u << (pb & 7u));
        float qs = (float)(int)(signed char)(qf);
        float yv = qs * scale_p;
        sP[kg - (uint32_t)kbase][oo] = p + (yv - p);   // exact flip value
      }
    }
    __syncthreads();
    // Phase 2: lanes 0..31 fold this half's 144 rows, carry held in register.
    if (tid < TO) {
      float c = carry;
#pragma unroll 8
      for (int kk = 0; kk < KH; ++kk) {
        c += sP[kk][tid];                   // exact reference fold order
        sP[kk][tid] = c;
        maxc = fmaxf(maxc, fabsf(c));
      }
      carry = c;
    }
    if (tid == 255) sCnt = 0u;              // reset for next half (disjoint from fold)
    __syncthreads();
    // Phase 3: write-out, float4-batch layout.
    // c[k][outi] -> cws[((k/4)*NOUT + outi)*4 + k%4]
    for (int b = s; b < 36; b += 8) {
      int gb = half * 36 + b;
      float4 v0 = {sP[b * 4 + 0][o], sP[b * 4 + 1][o],
                   sP[b * 4 + 2][o], sP[b * 4 + 3][o]};
      float* op = cws + ((size_t)gb * NOUT + outi) * 4u;
      *(float4*)op = v0;
    }
    __syncthreads();                        // next half overwrites sP
  }
  // maxc lives in lanes 0..31 of wave 0; lanes 32..63 hold 0 -> full-wave reduce.
  if (tid < 64) {
#pragma unroll
    for (int off = 32; off > 0; off >>= 1)
      maxc = fmaxf(maxc, __shfl_down(maxc, off));
    if (tid == 0) atomicMax(maxc_bits, __float_as_uint(maxc));
  }
}

// ---------- k_fi2split: FI2 on c — 32 outi x 8 k-groups, grid 6272 ----------
// Rolled loop, float4 batches, 4-wide SoA ciphers. k=0 exclusion and
// k=287->ys are post-loop corrections (recompute + subtract, cancellation to
// reassociation-ulp). Flip fix routes kx==287 to ys-corr, drops kx==0.
__global__ __launch_bounds__(256) void k_fi2split(const float* __restrict__ cws,
                                                  const unsigned int* __restrict__ scal,
                                                  unsigned int* __restrict__ maxy_bits,
                                                  float* __restrict__ yout,
                                                  uint32_t ku0, uint32_t ku1,
                                                  uint32_t kp0, uint32_t kp1) {
#pragma clang fp contract(off)
  __shared__ float sE[8][TO];
  __shared__ float sYs[TO];
  __shared__ float sEC[TO];                 // flip corrections to e
  __shared__ float sYsC[TO];                // flip correction to ys (k=287)
  __shared__ uint32_t sCnt;
  __shared__ uint32_t sMeta[FCAP2];         // (k<<5)|o
  __shared__ float    sVal[FCAP2];          // c value of flipped element
  int tid = threadIdx.x;
  int o = tid & 31;
  int kg = tid >> 5;                        // 0..7
  if (tid < TO) { sEC[tid] = 0.f; sYsC[tid] = 0.f; }
  if (tid == 0) sCnt = 0u;
  __syncthreads();
  uint32_t outi = blockIdx.x * (uint32_t)TO + (uint32_t)o;   // 6272*32 = NOUT
  float scale_c = __uint_as_float(scal[2]) / 127.0f + 1e-12f;
  float rs_c = 1.0f / scale_c;
  uint32_t ibb = outi * (uint32_t)KK;
  const size_t BSTR = (size_t)NOUT * 4u;    // float stride between k-batches
  float e = 0.f;

  int b0 = kg * 9;                          // 9 float4-batches (36 k's) per group
  const float* bp = cws + (size_t)outi * 4u + (size_t)b0 * BSTR;
  uint32_t ib = ibb + (uint32_t)(b0 * 4);
  uint32_t kbm = (uint32_t)(b0 * 4);
  for (int b = 0; b < 9; ++b) {
    float4 A = *(const float4*)bp;
    float c4[4] = {A.x, A.y, A.z, A.w};
    uint32_t ub[4];
    rbits_n<4>(ku0, ku1, ib, ub);           // 4 interleaved chains
#pragma unroll
    for (int j = 0; j < 4; ++j) {
      float c = c4[j];
      float q = qround(c, scale_c, rs_c);   // exact RN(c/scale_c), clamp dead
      float y = q * scale_c;
      float cf = c + (y - c);               // skip-path fi value
      e += (cf - c);
      bool flip = ub[j] < FLIP_LT;
      if (__any(flip)) {                    // vcc branch, no exec write when clear
        if (flip) {
          uint32_t idx = atomicAdd(&sCnt, 1u);
          if (idx < FCAP2) {
            sMeta[idx] = ((kbm + (uint32_t)j) << 5) | (uint32_t)o;
            sVal[idx] = c;
          }
        }
      }
    }
    bp += BSTR; ib += 4u; kbm += 4u;
  }

  float ys = 0.f;
  if (kg == 0) {
    // remove the k=0 skip term the loop added (reference excludes k=0 entirely)
    float c0 = cws[(size_t)outi * 4u];
    float q = qround(c0, scale_c, rs_c);
    float y = q * scale_c;
    float cf = c0 + (y - c0);
    e -= (cf - c0);
  } else if (kg == 7) {
    // reclaim k=287: loop added its skip term to e; it belongs to ys instead
    float c287 = cws[(size_t)outi * 4u + 71u * BSTR + 3u];
    float q = qround(c287, scale_c, rs_c);
    float y = q * scale_c;
    float cf = c287 + (y - c287);
    e -= (cf - c287);
    ys = cf;
  }
  sE[kg][o] = e;
  if (kg == 7) sYs[o] = ys;
  __syncthreads();
  // fix pass: dense pos-cipher for the ~74 flipped elements of this block
  {
    uint32_t n = sCnt; if (n > FCAP2) n = FCAP2;
    for (uint32_t i2 = (uint32_t)tid; i2 < n; i2 += 256u) {
      uint32_t meta = sMeta[i2];
      float c = sVal[i2];
      uint32_t kx = meta >> 5, ln = meta & 31u;
      uint32_t i0 = (blockIdx.x * (uint32_t)TO + ln) * (uint32_t)KK + kx;
      uint32_t pb = rbits(kp0, kp1, i0);
      float q = qround(c, scale_c, rs_c);
      uint32_t qt = ((uint32_t)(int)q) & 0xFFu;
      uint32_t qf = qt ^ (1u << (pb & 7u));
      float qs = (float)(int)(signed char)(qf);
      float yf = qs * scale_c;
      float cff = c + (yf - c);             // flip-path fi value
      float ysk = q * scale_c;
      float cfs = c + (ysk - c);            // skip value already folded into e/ys
      float corr = cff - cfs;
      if (kx == 287u)     sYsC[ln] = corr;  // unique writer per lane
      else if (kx != 0u)  atomicAdd(&sEC[ln], corr);
      // kx == 0: reference drops c_fi[0] entirely -> no correction
    }
  }
  __syncthreads();
  float maxy = 0.f;
  if (tid < TO) {
    float ee = sE[0][o];
#pragma unroll
    for (int g = 1; g < 8; ++g) ee += sE[g][o];
    float y = (sYs[o] + sYsC[o]) + (ee + sEC[o]);
    yout[outi] = y;
    maxy = fabsf(y);
  }
  maxy = block_max<256>(maxy);
  if (tid == 0) atomicMax(maxy_bits, __float_as_uint(maxy));
}

// ---------- fallback (small ws): fused FI1+cumsum, then recompute-FI2 ----------
__global__ __launch_bounds__(64) void k_passC_nostore(const float* __restrict__ x,
                                                      const float* __restrict__ w,
                                                      const unsigned int* __restrict__ scal,
                                                      unsigned int* __restrict__ maxc_bits,
                                                      uint32_t ku0, uint32_t ku1,
                                                      uint32_t kp0, uint32_t kp1) {
#pragma clang fp contract(off)
  __shared__ float sW[KK];
  int co = blockIdx.y;
  float scale_w = __uint_as_float(scal[0]) / 127.0f + 1e-12f;
  for (int i = threadIdx.x; i < KK; i += 64) sW[i] = wquant(w[co * KK + i], scale_w);
  __syncthreads();
  int l = blockIdx.x * 64 + threadIdx.x;
  float maxc = 0.f;
  if (l < LL) {
    float scale_p = __uint_as_float(scal[1]) / 127.0f + 1e-12f;
    int oy = l / WW, ox = l % WW;
    uint32_t base = (uint32_t)(co * LL + l) * KK;
    float c = 0.f;
    int k = 0;
    for (int ci = 0; ci < CI; ++ci) {
      const float* xr = x + ci * LL;
#pragma unroll
      for (int di = 0; di < 3; ++di) {
        int yy = oy + di - 1;
        bool yok = (yy >= 0) && (yy < HH);
#pragma unroll
        for (int dj = 0; dj < 3; ++dj, ++k) {
          int xx = ox + dj - 1;
          float xv = (yok && xx >= 0 && xx < WW) ? xr[yy * WW + xx] : 0.f;
          float p = xv * sW[k];
          uint32_t i0 = base + (uint32_t)k;
          uint32_t ub = rbits(ku0, ku1, i0);
          c += fi_fwd_skip(p, scale_p, ub, kp0, kp1, i0);
          maxc = fmaxf(maxc, fabsf(c));
        }
      }
    }
  }
  maxc = block_max<64>(maxc);
  if (threadIdx.x == 0) atomicMax(maxc_bits, __float_as_uint(maxc));
}

__global__ __launch_bounds__(256) void k_passD_rec(const float* __restrict__ x,
                                                   const float* __restrict__ w,
                                                   const unsigned int* __restrict__ scal,
                                                   unsigned int* __restrict__ maxy_bits,
                                                   float* __restrict__ yout,
                                                   uint32_t ku10, uint32_t ku11,
                                                   uint32_t kp10, uint32_t kp11,
                                                   uint32_t ku20, uint32_t ku21,
                                                   uint32_t kp20, uint32_t kp21) {
#pragma clang fp contract(off)
  __shared__ float sW[KK];
  int co = blockIdx.y;
  float scale_w = __uint_as_float(scal[0]) / 127.0f + 1e-12f;
  for (int i = threadIdx.x; i < KK; i += 256) sW[i] = wquant(w[co * KK + i], scale_w);
  __syncthreads();
  int l = blockIdx.x * 256 + threadIdx.x;
  float maxy = 0.f;
  if (l < LL) {
    float scale_p = __uint_as_float(scal[1]) / 127.0f + 1e-12f;
    float scale_c = __uint_as_float(scal[2]) / 127.0f + 1e-12f;
    int oy = l / WW, ox = l % WW;
    uint32_t base = (uint32_t)(co * LL + l) * KK;
    float c = 0.f, e = 0.f, ys = 0.f;
    int k = 0;
    for (int ci = 0; ci < CI; ++ci) {
      const float* xr = x + ci * LL;
#pragma unroll
      for (int di = 0; di < 3; ++di) {
        int yy = oy + di - 1;
        bool yok = (yy >= 0) && (yy < HH);
#pragma unroll
        for (int dj = 0; dj < 3; ++dj, ++k) {
          int xx = ox + dj - 1;
          float xv = (yok && xx >= 0 && xx < WW) ? xr[yy * WW + xx] : 0.f;
          float p = xv * sW[k];
          uint32_t i0 = base + (uint32_t)k;
          uint32_t ub1 = rbits(ku10, ku11, i0);
          c += fi_fwd_skip(p, scale_p, ub1, kp10, kp11, i0);
          uint32_t ub2 = rbits(ku20, ku21, i0);
          float cf = fi_fwd_skip(c, scale_c, ub2, kp20, kp21, i0);
          if (k >= 1 && k <= 286) e += (cf - c);
          if (k == 287)           ys = cf;
        }
      }
    }
    float y = ys + e;
    yout[co * LL + l] = y;
    maxy = fabsf(y);
  }
  maxy = block_max<256>(maxy);
  if (threadIdx.x == 0) atomicMax(maxy_bits, __float_as_uint(maxy));
}

// ---------- pass E: FI3 on y, in place in d_out ----------
__global__ __launch_bounds__(256) void k_passE(float* __restrict__ y,
                                               const unsigned int* __restrict__ scal,
                                               uint32_t ku0, uint32_t ku1,
                                               uint32_t kp0, uint32_t kp1) {
#pragma clang fp contract(off)
  uint32_t i = blockIdx.x * 256u + threadIdx.x;
  float scale_y = __uint_as_float(scal[3]) / 127.0f + 1e-12f;
  uint32_t ub = rbits(ku0, ku1, i);
  y[i] = fi_fwd_skip(y[i], scale_y, ub, kp0, kp1, i);
}

extern "C" void kernel_launch(void* const* d_in, const int* in_sizes, int n_in,
                              void* d_out, int out_size, void* d_ws, size_t ws_size,
                              hipStream_t stream) {
  const float* x = (const float*)d_in[0];   // (1,32,56,56)
  const float* w = (const float*)d_in[1];   // (64,32,3,3)
  float* out = (float*)d_out;               // (1,64,56,56)

  unsigned int* scal = (unsigned int*)d_ws; // [0]=max|w| [1]=max|p| [2]=max|c| [3]=max|y|
  float* cws = (float*)d_ws + CWS_OFF_FLOATS;
  bool bigws = ws_size >= WS_NEED;          // constant across calls -> graph-safe

  // ---- exact JAX key derivation, partitionable threefry ----
  uint32_t K1[2], K2[2], K3[2];
  tf2x32(0u, 42u, 0u, 0u, K1[0], K1[1]);    // split(key(42), 3)
  tf2x32(0u, 42u, 0u, 1u, K2[0], K2[1]);
  tf2x32(0u, 42u, 0u, 2u, K3[0], K3[1]);
  auto derive = [](const uint32_t kk[2], uint32_t U[2], uint32_t P[2]) {
    uint32_t kA0, kA1, kB0, kB1, t0, t1;
    tf2x32(kk[0], kk[1], 0u, 0u, kA0, kA1); // split(key,2)[0] -> uniform key
    tf2x32(kk[0], kk[1], 0u, 1u, kB0, kB1); // split(key,2)[1] -> randint key
    U[0] = kA0; U[1] = kA1;
    tf2x32(kB0, kB1, 0u, 1u, t0, t1);       // randint lower-bits key
    P[0] = t0; P[1] = t1;
  };
  uint32_t U1[2],P1[2],U2[2],P2[2],U3[2],P3[2];
  derive(K1, U1, P1); derive(K2, U2, P2); derive(K3, U3, P3);

  hipMemsetAsync(d_ws, 0, 64, stream);      // zero the atomic-max slots

  k_wmax<<<72, 256, 0, stream>>>(w, scal);          // 72*256 = 18432 exact
  k_maxp<<<KK, 256, 0, stream>>>(x, w, scal, scal + 1);
  if (bigws) {
    k_fi1cs<<<NOUT / TO, 256, 0, stream>>>(x, w, scal, scal + 2, cws,
                                           U1[0], U1[1], P1[0], P1[1]);
    k_fi2split<<<NOUT / TO, 256, 0, stream>>>(cws, scal, scal + 3, out,
                                              U2[0], U2[1], P2[0], P2[1]);
  } else {
    dim3 gC(49, 64);
    k_passC_nostore<<<gC, 64, 0, stream>>>(x, w, scal, scal + 2,
                                           U1[0], U1[1], P1[0], P1[1]);
    dim3 gR(13, 64);
    k_passD_rec<<<gR, 256, 0, stream>>>(x, w, scal, scal + 3, out,
                                        U1[0], U1[1], P1[0], P1[1],
                                        U2[0], U2[1], P2[0], P2[1]);
  }
  k_passE<<<NOUT / 256, 256, 0, stream>>>(out, scal,
                                          U3[0], U3[1], P3[0], P3[1]);
}

// Round 6
// 341.751 us; speedup vs baseline: 1.0392x; 1.0060x over previous
//
#include <hip/hip_runtime.h>
#include <cstdint>

#define CO   64
#define CI   32
#define HH   56
#define WW   56
#define LL   3136        // 56*56
#define KK   288         // 32*9
#define KH   144         // KK/2 — double-pumped LDS tile
#define NOUT 200704u     // 64*3136
#define TO   32          // outi-tile per block

// flip threshold: u < 0.008f  <=>  ub < 67109*512
#define FLIP_LT 34359808u

// flip-list capacities. fi1: Binomial(4608,0.008) mean 37 -> 320 is ~47 sigma.
// fi2: Binomial(9216,0.008) mean 74 -> 320 is ~29 sigma. Unreachable.
#define FCAP1 320
#define FCAP2 320

// workspace layout: [0..63] atomic-max slots | 81920.. c_ws
// c_ws: float4 batches — c[k][outi] stored at [(k/4)*NOUT + outi]*4 + k%4
#define CWS_OFF_FLOATS 20480u                 // 81920 / 4
#define WS_NEED (81920ull + 4ull * 288ull * 200704ull)

__host__ __device__ inline uint32_t rotl32(uint32_t v, uint32_t r) {
#ifdef __HIP_DEVICE_COMPILE__
  return __builtin_amdgcn_alignbit(v, v, 32u - r);   // (v:v)>>(32-r) = rotl(v,r)
#else
  return (v << r) | (v >> (32u - r));
#endif
}

// ---------- threefry2x32 cipher, exact JAX rotation/key schedule ----------
__host__ __device__ inline void tf2x32(uint32_t k0, uint32_t k1,
                                       uint32_t x0, uint32_t x1,
                                       uint32_t& o0, uint32_t& o1) {
  uint32_t ks2 = k0 ^ k1 ^ 0x1BD11BDAu;
  uint32_t v0 = x0 + k0, v1 = x1 + k1;
#define TF_R(r) { v0 += v1; v1 = rotl32(v1, r); v1 ^= v0; }
  TF_R(13) TF_R(15) TF_R(26) TF_R(6)
  v0 += k1;  v1 += ks2 + 1u;
  TF_R(17) TF_R(29) TF_R(16) TF_R(24)
  v0 += ks2; v1 += k0 + 2u;
  TF_R(13) TF_R(15) TF_R(26) TF_R(6)
  v0 += k0;  v1 += k1 + 3u;
  TF_R(17) TF_R(29) TF_R(16) TF_R(24)
  v0 += k1;  v1 += ks2 + 4u;
  TF_R(13) TF_R(15) TF_R(26) TF_R(6)
  v0 += ks2; v1 += k0 + 5u;
#undef TF_R
  o0 = v0; o1 = v1;
}

// partitionable-threefry random bits for flat index i (hi word of iota = 0)
__device__ inline uint32_t rbits(uint32_t k0, uint32_t k1, uint32_t i) {
  uint32_t o0, o1;
  tf2x32(k0, k1, 0u, i, o0, o1);
  return o0 ^ o1;
}

// N ciphers for consecutive indices ibase..ibase+N-1, SoA lockstep.
// Bit-identical per element to rbits(): same ops, chains independent.
template <int N>
__device__ inline void rbits_n(uint32_t k0, uint32_t k1, uint32_t ibase,
                               uint32_t out[N]) {
  uint32_t ks2 = k0 ^ k1 ^ 0x1BD11BDAu;
  uint32_t v0[N], v1[N];
#pragma unroll
  for (int j = 0; j < N; ++j) { v0[j] = k0; v1[j] = (ibase + (uint32_t)j) + k1; }
#define TFN_R(r) { _Pragma("unroll") \
  for (int j = 0; j < N; ++j) { v0[j] += v1[j]; v1[j] = rotl32(v1[j], (r)); v1[j] ^= v0[j]; } }
#define TFN_K(a, b, c) { _Pragma("unroll") \
  for (int j = 0; j < N; ++j) { v0[j] += (a); v1[j] += (b) + (c); } }
  TFN_R(13) TFN_R(15) TFN_R(26) TFN_R(6)  TFN_K(k1, ks2, 1u)
  TFN_R(17) TFN_R(29) TFN_R(16) TFN_R(24) TFN_K(ks2, k0, 2u)
  TFN_R(13) TFN_R(15) TFN_R(26) TFN_R(6)  TFN_K(k0, k1, 3u)
  TFN_R(17) TFN_R(29) TFN_R(16) TFN_R(24) TFN_K(k1, ks2, 4u)
  TFN_R(13) TFN_R(15) TFN_R(26) TFN_R(6)  TFN_K(ks2, k0, 5u)
#undef TFN_R
#undef TFN_K
#pragma unroll
  for (int j = 0; j < N; ++j) out[j] = v0[j] ^ v1[j];
}

// Markstein exact-division quantize step: rs must be RN(1/scale).
// Reproduces RN(x/scale); clamps dead because scale = max|x|/127+1e-12.
__device__ inline float qround(float xv, float scale, float rs) {
#pragma clang fp contract(off)
  float q0 = xv * rs;
  float er = fmaf(-scale, q0, xv);
  return rintf(fmaf(er, rs, q0));
}

// weight quantization, bit-identical to the original k_wquant body
__device__ inline float wquant(float wv, float scale_w) {
#pragma clang fp contract(off)
  float q = fminf(127.0f, fmaxf(-128.0f, rintf(wv / scale_w)));
  float y = q * scale_w;
  return wv + (y - wv);
}

// FI forward with wave-level pos-cipher skip (fallback path + passE).
__device__ inline float fi_fwd_skip(float x, float scale,
                                    uint32_t ub, uint32_t kp0, uint32_t kp1,
                                    uint32_t i0) {
#pragma clang fp contract(off)
  float q = rintf(x / scale);                    // round-half-even, IEEE div
  q = fminf(127.0f, fmaxf(-128.0f, q));
  bool flip = ub < FLIP_LT;
  float y;
  if (__any(flip)) {                             // wave-uniform branch
    uint32_t pb = rbits(kp0, kp1, i0);
    uint32_t qt = ((uint32_t)(int)q) & 0xFFu;
    uint32_t mask = flip ? (1u << (pb & 7u)) : 0u;
    uint32_t qf = qt ^ mask;
    float qs = (float)(int)(signed char)(qf);
    y = qs * scale;
  } else {
    y = q * scale;
  }
  return x + (y - x);                            // x + stop_grad(y - x)
}

template <int BS>
__device__ inline float block_max(float v) {
  __shared__ float s[BS];
  int t = threadIdx.x;
  __syncthreads();
  s[t] = v; __syncthreads();
  for (int o = BS / 2; o > 0; o >>= 1) {
    if (t < o) s[t] = fmaxf(s[t], s[t + o]);
    __syncthreads();
  }
  return s[0];
}

// ---------- kernel 1: max|w| (tiny, 72 blocks) ----------
__global__ __launch_bounds__(256) void k_wmax(const float* __restrict__ w,
                                              unsigned int* __restrict__ mbits) {
  int i = blockIdx.x * 256 + threadIdx.x;        // grid 72 -> exactly 18432
  float m = fabsf(w[i]);
  m = block_max<256>(m);
  if (threadIdx.x == 0) atomicMax(mbits, __float_as_uint(m));
}

// ---------- kernel 2: max|p| = max_k (max_l|xc[l,k]| * max_co|wq[co,k]|) -------
__global__ __launch_bounds__(256) void k_maxp(const float* __restrict__ x,
                                              const float* __restrict__ w,
                                              const unsigned int* __restrict__ scal,
                                              unsigned int* __restrict__ maxp_bits) {
#pragma clang fp contract(off)
  int k = blockIdx.x;                       // 0..287
  int ci = k / 9, r = k % 9, di = r / 3, dj = r % 3;
  const float* xr = x + ci * LL;
  float scale_w = __uint_as_float(scal[0]) / 127.0f + 1e-12f;
  float mx = 0.f;
  for (int l = threadIdx.x; l < LL; l += 256) {
    int oy = l / WW, ox = l % WW;
    int yy = oy + di - 1, xx = ox + dj - 1;
    float v = (yy >= 0 && yy < HH && xx >= 0 && xx < WW) ? xr[yy * WW + xx] : 0.f;
    mx = fmaxf(mx, fabsf(v));
  }
  float mw = 0.f;
  for (int co = threadIdx.x; co < CO; co += 256)
    mw = fmaxf(mw, fabsf(wquant(w[co * KK + k], scale_w)));
  mx = block_max<256>(mx);
  mw = block_max<256>(mw);
  if (threadIdx.x == 0) atomicMax(maxp_bits, __float_as_uint(mx * mw));
}

// ---------- k_fi1cs: fused FI1 + serial cumsum, double-pumped LDS tile ----------
// Gather offsets/valid-masks hoisted to thread scope: per-element load is
// add + global_load + v_and (masked-zero ≡ the ternary-zero, bit-identical;
// OOB lanes read offset 0 of a valid channel, value discarded by the mask).
__global__ __launch_bounds__(256) void k_fi1cs(const float* __restrict__ x,
                                               const float* __restrict__ w,
                                               const unsigned int* __restrict__ scal,
                                               unsigned int* __restrict__ maxc_bits,
                                               float* __restrict__ cws,
                                               uint32_t ku0, uint32_t ku1,
                                               uint32_t kp0, uint32_t kp1) {
#pragma clang fp contract(off)
  __shared__ float sW[KK];                  // 1152 B
  __shared__ float sP[KH][TO];              // 18432 B
  __shared__ uint32_t sCnt;
  __shared__ uint32_t sMeta[FCAP1];         // (k<<5)|o
  __shared__ float    sVal[FCAP1];          // p value of flipped element
  int tid = threadIdx.x;
  uint32_t outi0 = blockIdx.x * (uint32_t)TO;
  int co = (int)(outi0 / (uint32_t)LL);     // block-uniform (32 | 3136)
  float scale_w = __uint_as_float(scal[0]) / 127.0f + 1e-12f;
  for (int i = tid; i < KK; i += 256) sW[i] = wquant(w[co * KK + i], scale_w);
  if (tid == 0) sCnt = 0u;
  __syncthreads();

  int o = tid & 31, s = tid >> 5;           // s in 0..7
  uint32_t outi = outi0 + (uint32_t)o;
  int l = (int)(outi - (uint32_t)co * LL);
  int oy = l / WW, ox = l % WW;
  float scale_p = __uint_as_float(scal[1]) / 127.0f + 1e-12f;
  float rs_p = 1.0f / scale_p;              // RN reciprocal, once per thread
  uint32_t ibase = outi * (uint32_t)KK;

  // hoisted 3x3 gather geometry: byte offsets within a channel + valid masks
  uint32_t goff[9], gmask[9];
#pragma unroll
  for (int di = 0; di < 3; ++di) {
    int yy = oy + di - 1;
    bool yok = (yy >= 0) && (yy < HH);
#pragma unroll
    for (int dj = 0; dj < 3; ++dj) {
      int xx = ox + dj - 1;
      bool ok = yok && (xx >= 0) && (xx < WW);
      int j = di * 3 + dj;
      goff[j] = ok ? (uint32_t)((yy * WW + xx) * 4) : 0u;
      gmask[j] = ok ? 0xFFFFFFFFu : 0u;
    }
  }
  const char* xb = (const char*)x;

  float carry = 0.f, maxc = 0.f;
  for (int half = 0; half < 2; ++half) {
    int kbase = half * KH;
    int k = kbase + s * 18;
    int ci0 = k / 9;                        // = 16*half + 2*s
    for (int c2 = 0; c2 < 2; ++c2) {
      uint32_t cb = (uint32_t)((ci0 + c2) * (LL * 4));  // channel byte offset
      float xv[9];
      uint32_t ub[9];
#pragma unroll
      for (int j = 0; j < 9; ++j) {
        float t = *(const float*)(xb + (cb + goff[j]));
        xv[j] = __uint_as_float(__float_as_uint(t) & gmask[j]);
      }
      rbits_n<9>(ku0, ku1, ibase + (uint32_t)k, ub);   // 9 interleaved chains
#pragma unroll
      for (int j = 0; j < 9; ++j) {
        float p = xv[j] * sW[k + j];
        float q = qround(p, scale_p, rs_p); // exact RN(p/scale_p), clamp dead
        float y = q * scale_p;
        sP[k + j - kbase][o] = p + (y - p); // skip-path fi value
        bool flip = ub[j] < FLIP_LT;
        if (__any(flip)) {                  // vcc branch, no exec write when clear
          if (flip) {
            uint32_t idx = atomicAdd(&sCnt, 1u);
            if (idx < FCAP1) {
              sMeta[idx] = ((uint32_t)(k + j) << 5) | (uint32_t)o;
              sVal[idx] = p;
            }
          }
        }
      }
      k += 9;
    }
    __syncthreads();
    // fix pass: dense pos-cipher for the ~37 flipped elements of this half
    {
      uint32_t n = sCnt; if (n > FCAP1) n = FCAP1;
      for (uint32_t i2 = (uint32_t)tid; i2 < n; i2 += 256u) {
        uint32_t meta = sMeta[i2];
        float p = sVal[i2];
        uint32_t kg = meta >> 5, oo = meta & 31u;
        uint32_t i0 = (outi0 + oo) * (uint32_t)KK + kg;
        uint32_t pb = rbits(kp0, kp1, i0);
        float q = qround(p, scale_p, rs_p);
        uint32_t qt = ((uint32_t)(int)q) & 0xFFu;
        uint32_t qf = qt ^ (1u << (pb & 7u));
        float qs = (float)(int)(signed char)(qf);
        float yv = qs * scale_p;
        sP[kg - (uint32_t)kbase][oo] = p + (yv - p);   // exact flip value
      }
    }
    __syncthreads();
    // Phase 2: lanes 0..31 fold this half's 144 rows, carry held in register.
    if (tid < TO) {
      float c = carry;
#pragma unroll 8
      for (int kk = 0; kk < KH; ++kk) {
        c += sP[kk][tid];                   // exact reference fold order
        sP[kk][tid] = c;
        maxc = fmaxf(maxc, fabsf(c));
      }
      carry = c;
    }
    if (tid == 255) sCnt = 0u;              // reset for next half (disjoint from fold)
    __syncthreads();
    // Phase 3: write-out, float4-batch layout.
    // c[k][outi] -> cws[((k/4)*NOUT + outi)*4 + k%4]
    for (int b = s; b < 36; b += 8) {
      int gb = half * 36 + b;
      float4 v0 = {sP[b * 4 + 0][o], sP[b * 4 + 1][o],
                   sP[b * 4 + 2][o], sP[b * 4 + 3][o]};
      float* op = cws + ((size_t)gb * NOUT + outi) * 4u;
      *(float4*)op = v0;
    }
    __syncthreads();                        // next half overwrites sP
  }
  // maxc lives in lanes 0..31 of wave 0; lanes 32..63 hold 0 -> full-wave reduce.
  if (tid < 64) {
#pragma unroll
    for (int off = 32; off > 0; off >>= 1)
      maxc = fmaxf(maxc, __shfl_down(maxc, off));
    if (tid == 0) atomicMax(maxc_bits, __float_as_uint(maxc));
  }
}

// ---------- k_fi2split: FI2 on c — 32 outi x 8 k-groups, grid 6272 ----------
// Rolled loop with explicit 1-deep load-ahead. sched_barrier(0) pins the
// next-batch load ABOVE the current batch's compute so the compiler cannot
// sink it back to its use (round-2 failure mode); the waitcnt lands at the
// next iteration's consume -> ~600 cycles of cipher cover the load latency.
__global__ __launch_bounds__(256) void k_fi2split(const float* __restrict__ cws,
                                                  const unsigned int* __restrict__ scal,
                                                  unsigned int* __restrict__ maxy_bits,
                                                  float* __restrict__ yout,
                                                  uint32_t ku0, uint32_t ku1,
                                                  uint32_t kp0, uint32_t kp1) {
#pragma clang fp contract(off)
  __shared__ float sE[8][TO];
  __shared__ float sYs[TO];
  __shared__ float sEC[TO];                 // flip corrections to e
  __shared__ float sYsC[TO];                // flip correction to ys (k=287)
  __shared__ uint32_t sCnt;
  __shared__ uint32_t sMeta[FCAP2];         // (k<<5)|o
  __shared__ float    sVal[FCAP2];          // c value of flipped element
  int tid = threadIdx.x;
  int o = tid & 31;
  int kg = tid >> 5;                        // 0..7
  if (tid < TO) { sEC[tid] = 0.f; sYsC[tid] = 0.f; }
  if (tid == 0) sCnt = 0u;
  __syncthreads();
  uint32_t outi = blockIdx.x * (uint32_t)TO + (uint32_t)o;   // 6272*32 = NOUT
  float scale_c = __uint_as_float(scal[2]) / 127.0f + 1e-12f;
  float rs_c = 1.0f / scale_c;
  uint32_t ibb = outi * (uint32_t)KK;
  const size_t BSTR = (size_t)NOUT * 4u;    // float stride between k-batches
  float e = 0.f;

  int b0 = kg * 9;                          // 9 float4-batches (36 k's) per group
  const float* bp = cws + (size_t)outi * 4u + (size_t)b0 * BSTR;
  uint32_t ib = ibb + (uint32_t)(b0 * 4);
  uint32_t kbm = (uint32_t)(b0 * 4);

  auto body = [&](float4 A, uint32_t ibv, uint32_t kbmv) {
    float c4[4] = {A.x, A.y, A.z, A.w};
    uint32_t ub[4];
    rbits_n<4>(ku0, ku1, ibv, ub);          // 4 interleaved chains
#pragma unroll
    for (int j = 0; j < 4; ++j) {
      float c = c4[j];
      float q = qround(c, scale_c, rs_c);   // exact RN(c/scale_c), clamp dead
      float y = q * scale_c;
      float cf = c + (y - c);               // skip-path fi value
      e += (cf - c);
      bool flip = ub[j] < FLIP_LT;
      if (__any(flip)) {                    // vcc branch, no exec write when clear
        if (flip) {
          uint32_t idx = atomicAdd(&sCnt, 1u);
          if (idx < FCAP2) {
            sMeta[idx] = ((kbmv + (uint32_t)j) << 5) | (uint32_t)o;
            sVal[idx] = c;
          }
        }
      }
    }
  };

  float4 A = *(const float4*)bp;            // batch b0
  for (int b = 0; b < 8; ++b) {
    float4 An = *(const float4*)(bp + BSTR);   // issue next-batch load (<=71: valid)
    __builtin_amdgcn_sched_barrier(0);         // pin load issue above compute
    body(A, ib, kbm);
    A = An; bp += BSTR; ib += 4u; kbm += 4u;
  }
  body(A, ib, kbm);                         // last batch (b0+8)

  float ys = 0.f;
  if (kg == 0) {
    // remove the k=0 skip term the loop added (reference excludes k=0 entirely)
    float c0 = cws[(size_t)outi * 4u];
    float q = qround(c0, scale_c, rs_c);
    float y = q * scale_c;
    float cf = c0 + (y - c0);
    e -= (cf - c0);
  } else if (kg == 7) {
    // reclaim k=287: loop added its skip term to e; it belongs to ys instead
    float c287 = cws[(size_t)outi * 4u + 71u * BSTR + 3u];
    float q = qround(c287, scale_c, rs_c);
    float y = q * scale_c;
    float cf = c287 + (y - c287);
    e -= (cf - c287);
    ys = cf;
  }
  sE[kg][o] = e;
  if (kg == 7) sYs[o] = ys;
  __syncthreads();
  // fix pass: dense pos-cipher for the ~74 flipped elements of this block
  {
    uint32_t n = sCnt; if (n > FCAP2) n = FCAP2;
    for (uint32_t i2 = (uint32_t)tid; i2 < n; i2 += 256u) {
      uint32_t meta = sMeta[i2];
      float c = sVal[i2];
      uint32_t kx = meta >> 5, ln = meta & 31u;
      uint32_t i0 = (blockIdx.x * (uint32_t)TO + ln) * (uint32_t)KK + kx;
      uint32_t pb = rbits(kp0, kp1, i0);
      float q = qround(c, scale_c, rs_c);
      uint32_t qt = ((uint32_t)(int)q) & 0xFFu;
      uint32_t qf = qt ^ (1u << (pb & 7u));
      float qs = (float)(int)(signed char)(qf);
      float yf = qs * scale_c;
      float cff = c + (yf - c);             // flip-path fi value
      float ysk = q * scale_c;
      float cfs = c + (ysk - c);            // skip value already folded into e/ys
      float corr = cff - cfs;
      if (kx == 287u)     sYsC[ln] = corr;  // unique writer per lane
      else if (kx != 0u)  atomicAdd(&sEC[ln], corr);
      // kx == 0: reference drops c_fi[0] entirely -> no correction
    }
  }
  __syncthreads();
  float maxy = 0.f;
  if (tid < TO) {
    float ee = sE[0][o];
#pragma unroll
    for (int g = 1; g < 8; ++g) ee += sE[g][o];
    float y = (sYs[o] + sYsC[o]) + (ee + sEC[o]);
    yout[outi] = y;
    maxy = fabsf(y);
  }
  maxy = block_max<256>(maxy);
  if (tid == 0) atomicMax(maxy_bits, __float_as_uint(maxy));
}

// ---------- fallback (small ws): fused FI1+cumsum, then recompute-FI2 ----------
__global__ __launch_bounds__(64) void k_passC_nostore(const float* __restrict__ x,
                                                      const float* __restrict__ w,
                                                      const unsigned int* __restrict__ scal,
                                                      unsigned int* __restrict__ maxc_bits,
                                                      uint32_t ku0, uint32_t ku1,
                                                      uint32_t kp0, uint32_t kp1) {
#pragma clang fp contract(off)
  __shared__ float sW[KK];
  int co = blockIdx.y;
  float scale_w = __uint_as_float(scal[0]) / 127.0f + 1e-12f;
  for (int i = threadIdx.x; i < KK; i += 64) sW[i] = wquant(w[co * KK + i], scale_w);
  __syncthreads();
  int l = blockIdx.x * 64 + threadIdx.x;
  float maxc = 0.f;
  if (l < LL) {
    float scale_p = __uint_as_float(scal[1]) / 127.0f + 1e-12f;
    int oy = l / WW, ox = l % WW;
    uint32_t base = (uint32_t)(co * LL + l) * KK;
    float c = 0.f;
    int k = 0;
    for (int ci = 0; ci < CI; ++ci) {
      const float* xr = x + ci * LL;
#pragma unroll
      for (int di = 0; di < 3; ++di) {
        int yy = oy + di - 1;
        bool yok = (yy >= 0) && (yy < HH);
#pragma unroll
        for (int dj = 0; dj < 3; ++dj, ++k) {
          int xx = ox + dj - 1;
          float xv = (yok && xx >= 0 && xx < WW) ? xr[yy * WW + xx] : 0.f;
          float p = xv * sW[k];
          uint32_t i0 = base + (uint32_t)k;
          uint32_t ub = rbits(ku0, ku1, i0);
          c += fi_fwd_skip(p, scale_p, ub, kp0, kp1, i0);
          maxc = fmaxf(maxc, fabsf(c));
        }
      }
    }
  }
  maxc = block_max<64>(maxc);
  if (threadIdx.x == 0) atomicMax(maxc_bits, __float_as_uint(maxc));
}

__global__ __launch_bounds__(256) void k_passD_rec(const float* __restrict__ x,
                                                   const float* __restrict__ w,
                                                   const unsigned int* __restrict__ scal,
                                                   unsigned int* __restrict__ maxy_bits,
                                                   float* __restrict__ yout,
                                                   uint32_t ku10, uint32_t ku11,
                                                   uint32_t kp10, uint32_t kp11,
                                                   uint32_t ku20, uint32_t ku21,
                                                   uint32_t kp20, uint32_t kp21) {
#pragma clang fp contract(off)
  __shared__ float sW[KK];
  int co = blockIdx.y;
  float scale_w = __uint_as_float(scal[0]) / 127.0f + 1e-12f;
  for (int i = threadIdx.x; i < KK; i += 256) sW[i] = wquant(w[co * KK + i], scale_w);
  __syncthreads();
  int l = blockIdx.x * 256 + threadIdx.x;
  float maxy = 0.f;
  if (l < LL) {
    float scale_p = __uint_as_float(scal[1]) / 127.0f + 1e-12f;
    float scale_c = __uint_as_float(scal[2]) / 127.0f + 1e-12f;
    int oy = l / WW, ox = l % WW;
    uint32_t base = (uint32_t)(co * LL + l) * KK;
    float c = 0.f, e = 0.f, ys = 0.f;
    int k = 0;
    for (int ci = 0; ci < CI; ++ci) {
      const float* xr = x + ci * LL;
#pragma unroll
      for (int di = 0; di < 3; ++di) {
        int yy = oy + di - 1;
        bool yok = (yy >= 0) && (yy < HH);
#pragma unroll
        for (int dj = 0; dj < 3; ++dj, ++k) {
          int xx = ox + dj - 1;
          float xv = (yok && xx >= 0 && xx < WW) ? xr[yy * WW + xx] : 0.f;
          float p = xv * sW[k];
          uint32_t i0 = base + (uint32_t)k;
          uint32_t ub1 = rbits(ku10, ku11, i0);
          c += fi_fwd_skip(p, scale_p, ub1, kp10, kp11, i0);
          uint32_t ub2 = rbits(ku20, ku21, i0);
          float cf = fi_fwd_skip(c, scale_c, ub2, kp20, kp21, i0);
          if (k >= 1 && k <= 286) e += (cf - c);
          if (k == 287)           ys = cf;
        }
      }
    }
    float y = ys + e;
    yout[co * LL + l] = y;
    maxy = fabsf(y);
  }
  maxy = block_max<256>(maxy);
  if (threadIdx.x == 0) atomicMax(maxy_bits, __float_as_uint(maxy));
}

// ---------- pass E: FI3 on y, in place in d_out ----------
__global__ __launch_bounds__(256) void k_passE(float* __restrict__ y,
                                               const unsigned int* __restrict__ scal,
                                               uint32_t ku0, uint32_t ku1,
                                               uint32_t kp0, uint32_t kp1) {
#pragma clang fp contract(off)
  uint32_t i = blockIdx.x * 256u + threadIdx.x;
  float scale_y = __uint_as_float(scal[3]) / 127.0f + 1e-12f;
  uint32_t ub = rbits(ku0, ku1, i);
  y[i] = fi_fwd_skip(y[i], scale_y, ub, kp0, kp1, i);
}

extern "C" void kernel_launch(void* const* d_in, const int* in_sizes, int n_in,
                              void* d_out, int out_size, void* d_ws, size_t ws_size,
                              hipStream_t stream) {
  const float* x = (const float*)d_in[0];   // (1,32,56,56)
  const float* w = (const float*)d_in[1];   // (64,32,3,3)
  float* out = (float*)d_out;               // (1,64,56,56)

  unsigned int* scal = (unsigned int*)d_ws; // [0]=max|w| [1]=max|p| [2]=max|c| [3]=max|y|
  float* cws = (float*)d_ws + CWS_OFF_FLOATS;
  bool bigws = ws_size >= WS_NEED;          // constant across calls -> graph-safe

  // ---- exact JAX key derivation, partitionable threefry ----
  uint32_t K1[2], K2[2], K3[2];
  tf2x32(0u, 42u, 0u, 0u, K1[0], K1[1]);    // split(key(42), 3)
  tf2x32(0u, 42u, 0u, 1u, K2[0], K2[1]);
  tf2x32(0u, 42u, 0u, 2u, K3[0], K3[1]);
  auto derive = [](const uint32_t kk[2], uint32_t U[2], uint32_t P[2]) {
    uint32_t kA0, kA1, kB0, kB1, t0, t1;
    tf2x32(kk[0], kk[1], 0u, 0u, kA0, kA1); // split(key,2)[0] -> uniform key
    tf2x32(kk[0], kk[1], 0u, 1u, kB0, kB1); // split(key,2)[1] -> randint key
    U[0] = kA0; U[1] = kA1;
    tf2x32(kB0, kB1, 0u, 1u, t0, t1);       // randint lower-bits key
    P[0] = t0; P[1] = t1;
  };
  uint32_t U1[2],P1[2],U2[2],P2[2],U3[2],P3[2];
  derive(K1, U1, P1); derive(K2, U2, P2); derive(K3, U3, P3);

  hipMemsetAsync(d_ws, 0, 64, stream);      // zero the atomic-max slots

  k_wmax<<<72, 256, 0, stream>>>(w, scal);          // 72*256 = 18432 exact
  k_maxp<<<KK, 256, 0, stream>>>(x, w, scal, scal + 1);
  if (bigws) {
    k_fi1cs<<<NOUT / TO, 256, 0, stream>>>(x, w, scal, scal + 2, cws,
                                           U1[0], U1[1], P1[0], P1[1]);
    k_fi2split<<<NOUT / TO, 256, 0, stream>>>(cws, scal, scal + 3, out,
                                              U2[0], U2[1], P2[0], P2[1]);
  } else {
    dim3 gC(49, 64);
    k_passC_nostore<<<gC, 64, 0, stream>>>(x, w, scal, scal + 2,
                                           U1[0], U1[1], P1[0], P1[1]);
    dim3 gR(13, 64);
    k_passD_rec<<<gR, 256, 0, stream>>>(x, w, scal, scal + 3, out,
                                        U1[0], U1[1], P1[0], P1[1],
                                        U2[0], U2[1], P2[0], P2[1]);
  }
  k_passE<<<NOUT / 256, 256, 0, stream>>>(out, scal,
                                          U3[0], U3[1], P3[0], P3[1]);
}